// Round 1
// baseline (69224.225 us; speedup 1.0000x reference)
//
#include <hip/hip_runtime.h>

#define NB     64
#define TMEL   1000
#define TE     400
#define ENC    512
#define MELD   80
#define P1     128
#define P2     64
#define HID    256
#define G4     1024   // 4*HID
#define KCOMB  832    // 64 + 512 + 256

// ws layout (float offsets)
#define OFF_WQT   0                        // 256*512   = 131072  (wqT[k*512+j])
#define OFF_COMBT (OFF_WQT + 131072)       // 832*1024  = 851968  (combT[k*1024+j])
#define OFF_WOT   (OFF_COMBT + 851968)     // 256*80    = 20480   (woT[k*80+m])
#define OFF_WP1T  (OFF_WOT + 20480)        // 80*128    = 10240
#define OFF_WP2T  (OFF_WP1T + 10240)       // 128*64    = 8192
#define OFF_BSUM  (OFF_WP2T + 8192)        // 1024
#define OFF_X     (OFF_BSUM + 1024)        // 64*1000*64 = 4096000
#define PREP_TOT  (131072 + 851968 + 20480 + 10240 + 8192 + 1024)

__device__ __forceinline__ float fast_tanh(float x) {
    float e = __expf(2.f * x);
    return 1.f - 2.f * __builtin_amdgcn_rcpf(e + 1.f);
}
__device__ __forceinline__ float fast_sigmoid(float x) {
    return __builtin_amdgcn_rcpf(1.f + __expf(-x));
}

// ---------------- prep: transpose weights into ws ----------------
__global__ void prep_kernel(const float* __restrict__ Wq,
                            const float* __restrict__ Wih,
                            const float* __restrict__ Whh,
                            const float* __restrict__ Wout,
                            const float* __restrict__ Wp1,
                            const float* __restrict__ Wp2,
                            const float* __restrict__ bih,
                            const float* __restrict__ bhh,
                            float* __restrict__ ws) {
    int i = blockIdx.x * blockDim.x + threadIdx.x;
    if (i >= PREP_TOT) return;
    if (i < 131072) {                       // wqT[k*512+j] = Wq[j*256+k]
        int j = i & 511, k = i >> 9;
        ws[OFF_WQT + i] = Wq[j * 256 + k];
    } else if (i < 131072 + 851968) {       // combT[k*1024+j]
        int r = i - 131072;
        int j = r & 1023, k = r >> 10;
        float v = (k < 576) ? Wih[j * 576 + k] : Whh[j * 256 + (k - 576)];
        ws[OFF_COMBT + r] = v;
    } else if (i < 131072 + 851968 + 20480) { // woT[k*80+m] = Wout[m*256+k]
        int r = i - (131072 + 851968);
        int m = r % 80, k = r / 80;
        ws[OFF_WOT + r] = Wout[m * 256 + k];
    } else if (i < 131072 + 851968 + 20480 + 10240) { // wp1T[k*128+j]
        int r = i - (131072 + 851968 + 20480);
        int j = r & 127, k = r >> 7;
        ws[OFF_WP1T + r] = Wp1[j * 80 + k];
    } else if (i < 131072 + 851968 + 20480 + 10240 + 8192) { // wp2T[k*64+j]
        int r = i - (131072 + 851968 + 20480 + 10240);
        int j = r & 63, k = r >> 6;
        ws[OFF_WP2T + r] = Wp2[j * 128 + k];
    } else {                                 // bsum
        int r = i - (131072 + 851968 + 20480 + 10240 + 8192);
        ws[OFF_BSUM + r] = bih[r] + bhh[r];
    }
}

// ---------------- prenet: x[b,t,64] ----------------
__global__ __launch_bounds__(128) void prenet_kernel(const float* __restrict__ mel,
                                                     const float* __restrict__ bp1,
                                                     const float* __restrict__ bp2,
                                                     float* __restrict__ ws) {
    __shared__ float mel_sh[MELD];
    __shared__ float hid_sh[P1];
    const float* wp1T = ws + OFF_WP1T;
    const float* wp2T = ws + OFF_WP2T;
    int bt = blockIdx.x;              // b*1000 + t
    int tid = threadIdx.x;
    if (tid < MELD) mel_sh[tid] = mel[(size_t)bt * MELD + tid];
    __syncthreads();
    {
        float acc = bp1[tid];
        #pragma unroll 4
        for (int k = 0; k < MELD; ++k) acc += mel_sh[k] * wp1T[k * P1 + tid];
        hid_sh[tid] = fmaxf(acc, 0.f);
    }
    __syncthreads();
    if (tid < P2) {
        float acc = bp2[tid];
        #pragma unroll 4
        for (int k = 0; k < P1; ++k) acc += hid_sh[k] * wp2T[k * P2 + tid];
        ws[OFF_X + (size_t)bt * P2 + tid] = fmaxf(acc, 0.f);
    }
}

// ---------------- persistent decoder: one block per batch elem ----------------
__global__ __launch_bounds__(1024, 1) void decoder_kernel(const float* __restrict__ enc,
                                                          const float* __restrict__ bq,
                                                          const float* __restrict__ we,
                                                          const float* __restrict__ bout,
                                                          const float* __restrict__ ws,
                                                          float* __restrict__ out) {
    __shared__ __align__(16) float h_sh[HID];
    __shared__ __align__(16) float c_sh[HID];
    __shared__ __align__(16) float q_sh[ENC];
    __shared__ __align__(16) float lin_sh[KCOMB];
    __shared__ __align__(16) float en_sh[TE];
    __shared__ __align__(16) float gates_sh[G4];
    __shared__ __align__(16) float scr[4096];
    __shared__ float red_sh[2];

    const int b    = blockIdx.x;
    const int tid  = threadIdx.x;
    const int lane = tid & 63;
    const int wv   = tid >> 6;

    const float* wqT   = ws + OFF_WQT;
    const float* combT = ws + OFF_COMBT;
    const float* woT   = ws + OFF_WOT;
    const float* bsum  = ws + OFF_BSUM;
    const float* xin   = ws + OFF_X + (size_t)b * TMEL * P2;
    const float* encB  = enc + (size_t)b * TE * ENC;
    float*       outB  = out + (size_t)b * TMEL * MELD;

    if (tid < HID) { h_sh[tid] = 0.f; c_sh[tid] = 0.f; }
    __syncthreads();

    // w_e fragment per lane (constant across steps)
    float4 wa = ((const float4*)we)[lane];
    float4 wb = ((const float4*)we)[lane + 64];

    for (int t = 0; t < TMEL; ++t) {
        // ---- q = h @ Wq^T + bq : 128 j-quads x 8 k-chunks of 32
        {
            int jq = tid & 127, kc = tid >> 7;
            float4 acc = {0.f, 0.f, 0.f, 0.f};
            int k0 = kc * 32;
            #pragma unroll 4
            for (int k = k0; k < k0 + 32; ++k) {
                float v = h_sh[k];
                float4 w4 = ((const float4*)(wqT + (size_t)k * ENC))[jq];
                acc.x += v * w4.x; acc.y += v * w4.y; acc.z += v * w4.z; acc.w += v * w4.w;
            }
            ((float4*)scr)[kc * 128 + jq] = acc;
        }
        __syncthreads();
        if (tid < ENC) {
            float v = bq[tid];
            #pragma unroll
            for (int kc = 0; kc < 8; ++kc) v += scr[kc * 512 + tid];
            q_sh[tid] = v;
        }
        __syncthreads();

        // ---- energy[te] = sum_k we[k] * tanh(q[k] + enc[te,k]) ; wave per 25 rows
        {
            float4 qa = ((const float4*)q_sh)[lane];
            float4 qb = ((const float4*)q_sh)[lane + 64];
            int te0 = wv * 25;
            for (int r = 0; r < 25; ++r) {
                int te = te0 + r;
                const float4* er = (const float4*)(encB + (size_t)te * ENC);
                float4 ea = er[lane];
                float4 eb = er[lane + 64];
                float p;
                p  = wa.x * fast_tanh(qa.x + ea.x);
                p += wa.y * fast_tanh(qa.y + ea.y);
                p += wa.z * fast_tanh(qa.z + ea.z);
                p += wa.w * fast_tanh(qa.w + ea.w);
                p += wb.x * fast_tanh(qb.x + eb.x);
                p += wb.y * fast_tanh(qb.y + eb.y);
                p += wb.z * fast_tanh(qb.z + eb.z);
                p += wb.w * fast_tanh(qb.w + eb.w);
                #pragma unroll
                for (int off = 32; off; off >>= 1) p += __shfl_xor(p, off, 64);
                if (lane == 0) en_sh[te] = p;
            }
        }
        __syncthreads();

        // ---- softmax max (wave 0)
        if (wv == 0) {
            float m = -1e30f;
            for (int i = lane; i < TE; i += 64) m = fmaxf(m, en_sh[i]);
            #pragma unroll
            for (int off = 32; off; off >>= 1) m = fmaxf(m, __shfl_xor(m, off, 64));
            if (lane == 0) red_sh[0] = m;
        }
        __syncthreads();
        if (tid < TE) en_sh[tid] = __expf(en_sh[tid] - red_sh[0]);
        __syncthreads();

        // ---- wave0: sum + rcp ; all: ctx partials over unnormalized ex
        if (wv == 0) {
            float s = 0.f;
            for (int i = lane; i < TE; i += 64) s += en_sh[i];
            #pragma unroll
            for (int off = 32; off; off >>= 1) s += __shfl_xor(s, off, 64);
            if (lane == 0) red_sh[1] = __builtin_amdgcn_rcpf(s);
        }
        {
            int kq = tid & 127, tc = tid >> 7;
            float4 acc = {0.f, 0.f, 0.f, 0.f};
            int t0 = tc * 50;
            #pragma unroll 2
            for (int r = 0; r < 50; ++r) {
                int te = t0 + r;
                float a = en_sh[te];
                float4 e4 = ((const float4*)(encB + (size_t)te * ENC))[kq];
                acc.x += a * e4.x; acc.y += a * e4.y; acc.z += a * e4.z; acc.w += a * e4.w;
            }
            ((float4*)scr)[tc * 128 + kq] = acc;
        }
        __syncthreads();

        // ---- build lstm_in = [x_t, ctx, h]
        if (tid < ENC) {
            float v = 0.f;
            #pragma unroll
            for (int tc = 0; tc < 8; ++tc) v += scr[tc * 512 + tid];
            lin_sh[64 + tid] = v * red_sh[1];
        } else if (tid < ENC + P2) {
            lin_sh[tid - ENC] = xin[(size_t)t * P2 + (tid - ENC)];
        } else if (tid < ENC + P2 + HID) {
            int k = tid - ENC - P2;
            lin_sh[576 + k] = h_sh[k];
        }
        __syncthreads();

        // ---- gates = lstm_in @ combT + bsum : 256 j-quads x 4 k-chunks of 208
        {
            int jq = tid & 255, kc = tid >> 8;
            float4 acc = {0.f, 0.f, 0.f, 0.f};
            int k0 = kc * 208;
            #pragma unroll 4
            for (int k = k0; k < k0 + 208; ++k) {
                float v = lin_sh[k];
                float4 w4 = ((const float4*)(combT + (size_t)k * G4))[jq];
                acc.x += v * w4.x; acc.y += v * w4.y; acc.z += v * w4.z; acc.w += v * w4.w;
            }
            ((float4*)scr)[kc * 256 + jq] = acc;
        }
        __syncthreads();
        gates_sh[tid] = scr[tid] + scr[1024 + tid] + scr[2048 + tid] + scr[3072 + tid] + bsum[tid];
        __syncthreads();

        // ---- LSTM pointwise
        if (tid < HID) {
            float ig = fast_sigmoid(gates_sh[tid]);
            float fg = fast_sigmoid(gates_sh[256 + tid]);
            float gg = fast_tanh(gates_sh[512 + tid]);
            float og = fast_sigmoid(gates_sh[768 + tid]);
            float cN = fg * c_sh[tid] + ig * gg;
            float hN = og * fast_tanh(cN);
            c_sh[tid] = cN;
            h_sh[tid] = hN;
        }
        __syncthreads();

        // ---- mel head: 80 outputs x 4 k-chunks of 64
        if (tid < 320) {
            int m = tid % 80, kc = tid / 80;
            float acc = 0.f;
            int k0 = kc * 64;
            #pragma unroll 4
            for (int k = k0; k < k0 + 64; ++k) acc += h_sh[k] * woT[(size_t)k * MELD + m];
            scr[tid] = acc;
        }
        __syncthreads();
        if (tid < MELD)
            outB[(size_t)t * MELD + tid] =
                scr[tid] + scr[80 + tid] + scr[160 + tid] + scr[240 + tid] + bout[tid];
        __syncthreads();
    }
}

extern "C" void kernel_launch(void* const* d_in, const int* in_sizes, int n_in,
                              void* d_out, int out_size, void* d_ws, size_t ws_size,
                              hipStream_t stream) {
    (void)in_sizes; (void)n_in; (void)out_size; (void)ws_size;
    const float* mel  = (const float*)d_in[0];
    const float* enc  = (const float*)d_in[1];
    const float* Wp1  = (const float*)d_in[2];
    const float* bp1  = (const float*)d_in[3];
    const float* Wp2  = (const float*)d_in[4];
    const float* bp2  = (const float*)d_in[5];
    const float* Wq   = (const float*)d_in[6];
    const float* bq   = (const float*)d_in[7];
    const float* We   = (const float*)d_in[8];
    // d_in[9] = b_e : constant shift, softmax-invariant -> unused
    const float* Wih  = (const float*)d_in[10];
    const float* Whh  = (const float*)d_in[11];
    const float* bih  = (const float*)d_in[12];
    const float* bhh  = (const float*)d_in[13];
    const float* Wout = (const float*)d_in[14];
    const float* bout = (const float*)d_in[15];
    float* ws  = (float*)d_ws;
    float* out = (float*)d_out;

    int prepBlocks = (PREP_TOT + 255) / 256;
    prep_kernel<<<prepBlocks, 256, 0, stream>>>(Wq, Wih, Whh, Wout, Wp1, Wp2, bih, bhh, ws);
    prenet_kernel<<<NB * TMEL, 128, 0, stream>>>(mel, bp1, bp2, ws);
    decoder_kernel<<<NB, 1024, 0, stream>>>(enc, bq, We, bout, ws, out);
}